// Round 20
// baseline (626.965 us; speedup 1.0000x reference)
//
#include <hip/hip_runtime.h>
#include <hip/hip_bf16.h>
#include <stdint.h>

#define BATCH 512
#define PIX   196
#define EDIM  2048
#define DDIM  512
#define ADIM  512
#define MROWS (BATCH*PIX)   // 100352 = 784*128

#define BM 128
#define BN 128
#define BK 32
#define NT (EDIM/BK)        // 64

typedef __attribute__((ext_vector_type(8))) short bf16x8;
typedef __attribute__((ext_vector_type(4))) unsigned short us4;
typedef __attribute__((ext_vector_type(8))) float f32x8;
typedef __attribute__((ext_vector_type(8))) __bf16 bf16v8;
typedef __attribute__((ext_vector_type(4))) float f32x4;

#define GLL16(g, lptr) __builtin_amdgcn_global_load_lds( \
    (const __attribute__((address_space(1))) void*)(g),  \
    (__attribute__((address_space(3))) void*)(lptr), 16, 0, 0)

static __device__ __forceinline__ unsigned short f2bf(float f) {
  union { float f; uint32_t u; } v; v.f = f;
  uint32_t u = v.u;
  return (unsigned short)((u + 0x7FFFu + ((u >> 16) & 1u)) >> 16);  // RNE
}

static __device__ __forceinline__ float bf2f(unsigned short u) {
  union { uint32_t u; float f; } v; v.u = ((uint32_t)u) << 16;
  return v.f;
}

// fp32x8 -> bf16x8 via compiler-selected v_cvt_pk_bf16_f32 (RNE)
static __device__ __forceinline__ bf16x8 cvt8(float4 a, float4 b) {
  f32x8 v = {a.x, a.y, a.z, a.w, b.x, b.y, b.z, b.w};
  bf16v8 c = __builtin_convertvector(v, bf16v8);
  bf16x8 r;
  __builtin_memcpy(&r, &c, 16);
  return r;
}

// tanh(x) = 1 - 2/(1+e^{2x}); exact at +-inf, ~1e-6 abs err (v_exp+v_rcp).
static __device__ __forceinline__ float tanh_fast(float x) {
  const float e = __expf(2.0f * x);
  const float r = __builtin_amdgcn_rcpf(1.0f + e);
  return __builtin_fmaf(-2.0f, r, 1.0f);
}

// ---------------- K0a: W_enc [2048][512] f32 -> Bt [512][2048] bf16 ----------
__global__ void k_transpose_wenc(const float* __restrict__ W,
                                 unsigned short* __restrict__ Bt) {
  __shared__ float tile[32][33];
  const int kt = blockIdx.x;
  const int nt = blockIdx.y;
  const int tx = threadIdx.x, ty = threadIdx.y;   // 32 x 8
#pragma unroll
  for (int j = 0; j < 4; j++)
    tile[ty + 8*j][tx] = W[(size_t)(kt*32 + ty + 8*j)*ADIM + nt*32 + tx];
  __syncthreads();
#pragma unroll
  for (int j = 0; j < 4; j++)
    Bt[(size_t)(nt*32 + ty + 8*j)*EDIM + kt*32 + tx] = f2bf(tile[tx][ty + 8*j]);
}

// ------ K0b: att2p = hidden @ W_dec + b_dec + b_enc (b_enc folded in) -------
__global__ void k_att2p(const float* __restrict__ H, const float* __restrict__ Wd,
                        const float* __restrict__ bd, const float* __restrict__ be,
                        float* __restrict__ att2p) {
  __shared__ float h[DDIM];
  const int b = blockIdx.x;
  const int t = threadIdx.x;            // 256
  h[t]       = H[(size_t)b*DDIM + t];
  h[t + 256] = H[(size_t)b*DDIM + t + 256];
  __syncthreads();
  float a0 = 0.f, a1 = 0.f;
#pragma unroll 8
  for (int k = 0; k < DDIM; k++) {
    const float hv = h[k];
    a0 += hv * Wd[(size_t)k*ADIM + t];
    a1 += hv * Wd[(size_t)k*ADIM + t + 256];
  }
  att2p[(size_t)b*ADIM + t]       = a0 + bd[t]       + be[t];
  att2p[(size_t)b*ADIM + t + 256] = a1 + bd[t + 256] + be[t + 256];
}

// ---------------- K0c: enc fp32 -> encbf bf16 (grid-stride, BW-bound) -------
__global__ __launch_bounds__(256) void k_preconvert(const float* __restrict__ in,
                                                    unsigned short* __restrict__ out,
                                                    long n8) {
  long i = (long)blockIdx.x * 256 + threadIdx.x;
  const long stride = (long)gridDim.x * 256;
  for (; i < n8; i += stride) {
    const float4* p = (const float4*)(in + i*8);
    const float4 a = p[0], b = p[1];
    *(bf16x8*)(out + i*8) = cvt8(a, b);
  }
}

// ---------------- K1-bf16: m97 GEMM, 3-buf counted vmcnt, fast epilogue -----
__global__ __launch_bounds__(256, 3) void k_gemm_bf16(
    const unsigned short* __restrict__ At,  // [M][2048] bf16 (encbf)
    const unsigned short* __restrict__ Bt,  // [512][2048] bf16
    const float* __restrict__ att2p,        // [B][512] (b_enc folded)
    const float* __restrict__ W_full,       // [512]
    float* __restrict__ scores)             // [M] (pre-zeroed, atomicAdd)
{
  __shared__ __align__(16) char ldsA[3*8192];   // [buf][128 rows][32 bf16]
  __shared__ __align__(16) char ldsB[3*8192];
  __shared__ float a2s[2][128];                 // att2p slices for <=2 batches

  const int t   = threadIdx.x;          // 0..255
  const int l   = t & 63;
  const int wid = t >> 6;               // 0..3
  const int wr  = wid >> 1;             // 0..1 (M)
  const int wc  = wid & 1;              // 0..1 (N)

  // XCD swizzle (nwg=3136=8*392), n-minor: 4 N-tiles of one M-tile run
  // consecutively on one XCD -> A-tile fetched once, L2-reused 4x.
  const int orig = blockIdx.x;
  const int tile = (orig & 7) * 392 + (orig >> 3);
  const int bm0 = (tile >> 2) * BM;
  const int bn0 = (tile & 3) * BN;

  // ---- att2p staging: rows bm0..bm0+127 span batches ab0..ab1 (<=2) ----
  const int ab0 = bm0 / 196;
  const int ab1 = (bm0 + BM - 1) / 196;
  {
    const int slot = t >> 7, c = t & 127;       // 256 threads = 2x128
    a2s[slot][c] = att2p[(size_t)(slot ? ab1 : ab0) * ADIM + bn0 + c];
  }

  // ---- staging maps: idx=j*256+t -> row=idx>>2, chunk c=idx&3;
  //      LDS (row,c) holds global chunk c^((row>>1)&3); dest linear idx*16 ----
  const int r0 = t >> 2, c0 = t & 3;
  const int cswz = (c0 ^ ((r0 >> 1) & 3)) * 8;
  const unsigned short* srcA0 = At + (size_t)(bm0 + r0      ) * EDIM + cswz;
  const unsigned short* srcA1 = At + (size_t)(bm0 + r0 + 64 ) * EDIM + cswz;
  const unsigned short* srcB0 = Bt + (size_t)(bn0 + r0      ) * EDIM + cswz;
  const unsigned short* srcB1 = Bt + (size_t)(bn0 + r0 + 64 ) * EDIM + cswz;
  const int d0 = wid * 1024;            // j=0 dest (+lane*16 implicit)
  const int d1 = 4096 + wid * 1024;     // j=1 dest

  // ---- fragment read addresses ----
  const int l15 = l & 15, hi = l >> 4;
  const int ck  = (hi ^ ((l15 >> 1) & 3)) * 16;
  const int baseA = wr*4096 + l15*64 + ck;   // + mi*1024 + buf*8192
  const int baseB = wc*4096 + l15*64 + ck;   // + ni*1024 + buf*8192

  f32x4 acc[4][4] = {};

#define STG(BUF, KT) do {                                        \
    GLL16(srcA0 + (size_t)(KT)*BK, ldsA + (BUF)*8192 + d0);      \
    GLL16(srcA1 + (size_t)(KT)*BK, ldsA + (BUF)*8192 + d1);      \
    GLL16(srcB0 + (size_t)(KT)*BK, ldsB + (BUF)*8192 + d0);      \
    GLL16(srcB1 + (size_t)(KT)*BK, ldsB + (BUF)*8192 + d1);      \
  } while (0)

#define CMP(BUF) do {                                            \
    bf16x8 af[4], bfr[4];                                        \
    _Pragma("unroll")                                            \
    for (int ni = 0; ni < 4; ni++)                               \
      bfr[ni] = *(const bf16x8*)(ldsB + (BUF)*8192 + ni*1024 + baseB); \
    _Pragma("unroll")                                            \
    for (int mi = 0; mi < 4; mi++)                               \
      af[mi] = *(const bf16x8*)(ldsA + (BUF)*8192 + mi*1024 + baseA); \
    _Pragma("unroll")                                            \
    for (int mi = 0; mi < 4; mi++)                               \
      _Pragma("unroll")                                          \
      for (int ni = 0; ni < 4; ni++)                             \
        acc[mi][ni] = __builtin_amdgcn_mfma_f32_16x16x32_bf16(   \
            af[mi], bfr[ni], acc[mi][ni], 0, 0, 0);              \
  } while (0)

#define TILE(T, BUF, BUF2) do {                                  \
    STG(BUF2, (T)+2);                                            \
    CMP(BUF);                                                    \
    asm volatile("s_waitcnt vmcnt(4)" ::: "memory");             \
    __builtin_amdgcn_s_barrier();                                \
  } while (0)

  // ---- prologue: stage tiles 0,1 ----
  STG(0, 0);
  STG(1, 1);
  asm volatile("s_waitcnt vmcnt(4)" ::: "memory");   // tile 0 done
  __builtin_amdgcn_s_barrier();

  // ---- tiles 0..61 (period 3) ----
  for (int kb = 0; kb < 60; kb += 3) {
    TILE(kb,     0, 2);
    TILE(kb + 1, 1, 0);
    TILE(kb + 2, 2, 1);
  }
  TILE(60, 0, 2);    // stages 62
  TILE(61, 1, 0);    // stages 63
  // ---- tile 62: nothing to stage; drain tile 63 ----
  CMP(2);
  asm volatile("s_waitcnt vmcnt(0)" ::: "memory");
  __builtin_amdgcn_s_barrier();
  // ---- tile 63 ----
  CMP(0);

  // ---- fast epilogue: scores += sum_cols tanh_fast(acc + att2p) * W_full ----
  float wf[4];
  int cidx[4];
#pragma unroll
  for (int ni = 0; ni < 4; ni++) {
    cidx[ni] = wc*64 + ni*16 + l15;
    wf[ni] = W_full[bn0 + cidx[ni]];
  }
#pragma unroll
  for (int mi = 0; mi < 4; mi++) {
#pragma unroll
    for (int e = 0; e < 4; e++) {
      const int row_l = wr*64 + mi*16 + hi*4 + e;
      const unsigned gr = (unsigned)(bm0 + row_l);
      const int slot = (int)(gr / 196u) - ab0;   // 0 or 1
      float s = 0.f;
#pragma unroll
      for (int ni = 0; ni < 4; ni++) {
        const float v = acc[mi][ni][e] + a2s[slot][cidx[ni]];
        s += tanh_fast(v) * wf[ni];
      }
      s += __shfl_xor(s, 1); s += __shfl_xor(s, 2);
      s += __shfl_xor(s, 4); s += __shfl_xor(s, 8);
      if (l15 == 0) atomicAdd(&scores[gr], s);
    }
  }
}

// -------- K2-fused: softmax (196) + context, grid (BATCH, 2) ----------------
// blockIdx.y selects a 1024-col half of EDIM; softmax (tiny 196-reduce) is
// recomputed by both halves; half 0 writes alpha. 1024 blocks -> 4/CU.
__global__ __launch_bounds__(256) void k_smctx_bf16(
    const unsigned short* __restrict__ encbf,
    float* __restrict__ sa,              // [512][196] scores in, alpha out
    float* __restrict__ ctx) {           // [512][2048]
  __shared__ float red[256];
  __shared__ float al[PIX];
  const int b = blockIdx.x, t = threadIdx.x;
  const int half = blockIdx.y;           // 0 or 1

  const float v = (t < PIX) ? sa[(size_t)b*PIX + t] : -1e30f;
  red[t] = v; __syncthreads();
  for (int s2 = 128; s2 > 0; s2 >>= 1) {
    if (t < s2) red[t] = fmaxf(red[t], red[t + s2]);
    __syncthreads();
  }
  const float m = red[0]; __syncthreads();
  const float e = (t < PIX) ? __expf(v - m) : 0.f;
  red[t] = e; __syncthreads();
  for (int s2 = 128; s2 > 0; s2 >>= 1) {
    if (t < s2) red[t] += red[t + s2];
    __syncthreads();
  }
  const float inv = 1.f / red[0];
  if (t < PIX) {
    const float a = e * inv;
    al[t] = a;
    if (half == 0) sa[(size_t)b*PIX + t] = a;
  }
  __syncthreads();

  // context for cols [half*1024, half*1024+1024): 4 cols/thread
  const unsigned short* ep = encbf + (size_t)b * PIX * EDIM + half*1024 + t*4;
  float a0 = 0.f, a1 = 0.f, a2 = 0.f, a3 = 0.f;
  for (int p = 0; p < PIX; p++) {
    const us4 vv = *(const us4*)(ep + (size_t)p * EDIM);
    const float a = al[p];
    a0 += a * bf2f(vv[0]); a1 += a * bf2f(vv[1]);
    a2 += a * bf2f(vv[2]); a3 += a * bf2f(vv[3]);
  }
  float4 o = {a0, a1, a2, a3};
  *(float4*)(ctx + (size_t)b * EDIM + half*1024 + t*4) = o;
}

// ================= FALLBACK PATH (fp32-A, used if ws too small) =============
__global__ void k_softmax(float* __restrict__ sa) {   // [512][196]
  __shared__ float red[256];
  const int b = blockIdx.x, t = threadIdx.x;
  const float v = (t < PIX) ? sa[(size_t)b*PIX + t] : -1e30f;
  red[t] = v; __syncthreads();
  for (int s2 = 128; s2 > 0; s2 >>= 1) {
    if (t < s2) red[t] = fmaxf(red[t], red[t + s2]);
    __syncthreads();
  }
  const float m = red[0]; __syncthreads();
  const float e = (t < PIX) ? __expf(v - m) : 0.f;
  red[t] = e; __syncthreads();
  for (int s2 = 128; s2 > 0; s2 >>= 1) {
    if (t < s2) red[t] += red[t + s2];
    __syncthreads();
  }
  const float inv = 1.f / red[0];
  if (t < PIX) sa[(size_t)b*PIX + t] = e * inv;
}

__global__ __launch_bounds__(256, 3) void k_gemm_scores(
    const float* __restrict__ enc, const unsigned short* __restrict__ Bt,
    const float* __restrict__ att2p, const float* __restrict__ W_full,
    float* __restrict__ scores) {
  __shared__ __align__(16) char ldsA[2*8192];
  __shared__ __align__(16) char ldsB[3*8192];
  __shared__ float a2s[2][128];
  const int t = threadIdx.x, l = t & 63, wid = t >> 6;
  const int wr = wid >> 1, wc = wid & 1;
  const int orig = blockIdx.x;
  const int tile = (orig & 7) * 392 + (orig >> 3);
  const int bm0 = (tile >> 2) * BM, bn0 = (tile & 3) * BN;
  const int ab0 = bm0 / 196;
  const int ab1 = (bm0 + BM - 1) / 196;
  {
    const int slot = t >> 7, c = t & 127;
    a2s[slot][c] = att2p[(size_t)(slot ? ab1 : ab0) * ADIM + bn0 + c];
  }
  const int arow = t >> 1;
  const float* srcA = enc + (size_t)(bm0 + arow) * EDIM + (t & 1) * 16;
  const int g0 = (t & 1) * 2;
  const int wA0 = arow*64 + (((g0    ) ^ ((arow >> 1) & 3)) * 16);
  const int wA1 = arow*64 + (((g0 + 1) ^ ((arow >> 1) & 3)) * 16);
  const unsigned short* srcB[2];
#pragma unroll
  for (int j = 0; j < 2; j++) {
    const int idx = j*256 + t; const int row = idx >> 2;
    srcB[j] = Bt + (size_t)(bn0 + row) * EDIM + ((idx & 3) ^ ((row >> 1) & 3)) * 8;
  }
  const int dB = wid * 1024;
  const int l15 = l & 15, hi = l >> 4;
  const int ck = (hi ^ ((l15 >> 1) & 3)) * 16;
  const int baseA = wr*4096 + l15*64 + ck;
  const int baseB = wc*4096 + l15*64 + ck;
  float4 ar[2][4];
  f32x4 acc[4][4] = {};
#define F_A_ISSUE(SLOT, KT) do { const float* _s = srcA + (size_t)(KT) * BK; \
    ar[SLOT][0] = *(const float4*)(_s); ar[SLOT][1] = *(const float4*)(_s + 4); \
    ar[SLOT][2] = *(const float4*)(_s + 8); ar[SLOT][3] = *(const float4*)(_s + 12); } while (0)
#define F_B_GLL(BUF, KT) do { \
    GLL16(srcB[0] + (size_t)(KT)*BK, ldsB + (BUF)*8192 + dB); \
    GLL16(srcB[1] + (size_t)(KT)*BK, ldsB + (BUF)*8192 + 4096 + dB); } while (0)
#define F_A_WRITE(LBUF, SLOT) do { \
    bf16x8 w0 = cvt8(ar[SLOT][0], ar[SLOT][1]); bf16x8 w1 = cvt8(ar[SLOT][2], ar[SLOT][3]); \
    *(bf16x8*)(ldsA + (LBUF)*8192 + wA0) = w0; *(bf16x8*)(ldsA + (LBUF)*8192 + wA1) = w1; } while (0)
#define F_COMPUTE(BA, BB) do { bf16x8 af[4], bfr[4]; \
    _Pragma("unroll") for (int ni = 0; ni < 4; ni++) \
      bfr[ni] = *(const bf16x8*)(ldsB + (BB)*8192 + ni*1024 + baseB); \
    _Pragma("unroll") for (int mi = 0; mi < 4; mi++) \
      af[mi] = *(const bf16x8*)(ldsA + (BA)*8192 + mi*1024 + baseA); \
    _Pragma("unroll") for (int mi = 0; mi < 4; mi++) \
      _Pragma("unroll") for (int ni = 0; ni < 4; ni++) \
        acc[mi][ni] = __builtin_amdgcn_mfma_f32_16x16x32_bf16(af[mi], bfr[ni], acc[mi][ni], 0, 0, 0); } while (0)
#define F_TILE(T, CUR, BB, BBS) do { F_A_ISSUE(CUR, (T)+2); F_B_GLL(BBS, (T)+2); \
    F_COMPUTE(CUR, BB); asm volatile("s_waitcnt vmcnt(6)" ::: "memory"); \
    F_A_WRITE((CUR)^1, (CUR)^1); asm volatile("s_waitcnt lgkmcnt(0)" ::: "memory"); \
    __builtin_amdgcn_s_barrier(); } while (0)
  F_A_ISSUE(0, 0); F_B_GLL(0, 0); F_A_ISSUE(1, 1); F_B_GLL(1, 1);
  asm volatile("s_waitcnt vmcnt(8)" ::: "memory");
  F_A_WRITE(0, 0);
  asm volatile("s_waitcnt vmcnt(6) lgkmcnt(0)" ::: "memory");
  __builtin_amdgcn_s_barrier();
  for (int kb = 0; kb < 60; kb += 6) {
    F_TILE(kb+0, 0, 0, 2); F_TILE(kb+1, 1, 1, 0); F_TILE(kb+2, 0, 2, 1);
    F_TILE(kb+3, 1, 0, 2); F_TILE(kb+4, 0, 1, 0); F_TILE(kb+5, 1, 2, 1);
  }
  F_TILE(60, 0, 0, 2); F_TILE(61, 1, 1, 0);
  { F_COMPUTE(0, 2); asm volatile("s_waitcnt vmcnt(2)" ::: "memory");
    F_A_WRITE(1, 1); asm volatile("s_waitcnt vmcnt(0) lgkmcnt(0)" ::: "memory");
    __builtin_amdgcn_s_barrier(); }
  F_COMPUTE(1, 0);
  float wf[4]; int cidx[4];
#pragma unroll
  for (int ni = 0; ni < 4; ni++) {
    cidx[ni] = wc*64 + ni*16 + l15;
    wf[ni] = W_full[bn0 + cidx[ni]];
  }
#pragma unroll
  for (int mi = 0; mi < 4; mi++) {
#pragma unroll
    for (int e = 0; e < 4; e++) {
      const int row_l = wr*64 + mi*16 + hi*4 + e;
      const unsigned gr = (unsigned)(bm0 + row_l);
      const int slot = (int)(gr / 196u) - ab0;
      float s = 0.f;
#pragma unroll
      for (int ni = 0; ni < 4; ni++) {
        const float v = acc[mi][ni][e] + a2s[slot][cidx[ni]];
        s += tanh_fast(v) * wf[ni];
      }
      s += __shfl_xor(s, 1); s += __shfl_xor(s, 2);
      s += __shfl_xor(s, 4); s += __shfl_xor(s, 8);
      if (l15 == 0) atomicAdd(&scores[gr], s);
    }
  }
}

__global__ __launch_bounds__(512) void k_context(
    const float* __restrict__ enc, const float* __restrict__ alpha,
    float* __restrict__ ctx) {
  __shared__ float al[PIX];
  const int b = blockIdx.x, t = threadIdx.x;
  if (t < PIX) al[t] = alpha[(size_t)b*PIX + t];
  __syncthreads();
  const float4* e4 = (const float4*)(enc + (size_t)b * PIX * EDIM);
  float4 acc = {0.f, 0.f, 0.f, 0.f};
#pragma unroll 4
  for (int p = 0; p < PIX; p++) {
    const float4 v = e4[(size_t)p * (EDIM/4) + t];
    const float a = al[p];
    acc.x += v.x * a; acc.y += v.y * a; acc.z += v.z * a; acc.w += v.w * a;
  }
  ((float4*)(ctx + (size_t)b * EDIM))[t] = acc;
}

// ---------------------------------------------------------------------------
extern "C" void kernel_launch(void* const* d_in, const int* in_sizes, int n_in,
                              void* d_out, int out_size, void* d_ws, size_t ws_size,
                              hipStream_t stream) {
  (void)in_sizes; (void)n_in; (void)out_size;
  const float* enc   = (const float*)d_in[0];
  const float* hid   = (const float*)d_in[1];
  const float* Wenc  = (const float*)d_in[2];
  const float* benc  = (const float*)d_in[3];
  const float* Wdec  = (const float*)d_in[4];
  const float* bdec  = (const float*)d_in[5];
  const float* Wfull = (const float*)d_in[6];
  // d_in[7] = b_full: softmax-invariant, unused.

  float* ctx   = (float*)d_out;
  float* alpha = (float*)d_out + (size_t)BATCH * EDIM;   // scores live here

  const size_t encbf_b = (size_t)MROWS * EDIM * 2;       // 411,041,792
  const size_t bt_b    = (size_t)ADIM * EDIM * 2;        //   2,097,152
  const size_t att2_b  = (size_t)BATCH * ADIM * 4;       //   1,048,576

  if (ws_size >= encbf_b + bt_b + att2_b) {
    // ---- bf16-preconvert path ----
    unsigned short* encbf = (unsigned short*)d_ws;
    unsigned short* Bt    = (unsigned short*)((char*)d_ws + encbf_b);
    float*          att2p = (float*)((char*)d_ws + encbf_b + bt_b);

    hipMemsetAsync(alpha, 0, (size_t)MROWS * sizeof(float), stream);
    k_transpose_wenc<<<dim3(64, 16), dim3(32, 8), 0, stream>>>(Wenc, Bt);
    k_att2p<<<BATCH, 256, 0, stream>>>(hid, Wdec, bdec, benc, att2p);
    k_preconvert<<<2048, 256, 0, stream>>>(enc, encbf, (long)MROWS * EDIM / 8);
    k_gemm_bf16<<<3136, 256, 0, stream>>>(encbf, Bt, att2p, Wfull, alpha);
    k_smctx_bf16<<<dim3(BATCH, 2), 256, 0, stream>>>(encbf, alpha, ctx);
  } else {
    // ---- fallback: fp32-A path ----
    unsigned short* Bt    = (unsigned short*)d_ws;
    float*          att2p = (float*)((char*)d_ws + bt_b);

    hipMemsetAsync(alpha, 0, (size_t)MROWS * sizeof(float), stream);
    k_transpose_wenc<<<dim3(64, 16), dim3(32, 8), 0, stream>>>(Wenc, Bt);
    k_att2p<<<BATCH, 256, 0, stream>>>(hid, Wdec, bdec, benc, att2p);
    k_gemm_scores<<<3136, 256, 0, stream>>>(enc, Bt, att2p, Wfull, alpha);
    k_softmax<<<BATCH, 256, 0, stream>>>(alpha);
    k_context<<<BATCH, 512, 0, stream>>>(enc, alpha, ctx);
  }
}

// Round 21
// 613.113 us; speedup vs baseline: 1.0226x; 1.0226x over previous
//
#include <hip/hip_runtime.h>
#include <hip/hip_bf16.h>
#include <stdint.h>

#define BATCH 512
#define PIX   196
#define EDIM  2048
#define DDIM  512
#define ADIM  512
#define MROWS (BATCH*PIX)   // 100352 = 784*128

#define BM 128
#define BN 128
#define BK 32
#define NT (EDIM/BK)        // 64

typedef __attribute__((ext_vector_type(8))) short bf16x8;
typedef __attribute__((ext_vector_type(4))) unsigned short us4;
typedef __attribute__((ext_vector_type(8))) float f32x8;
typedef __attribute__((ext_vector_type(8))) __bf16 bf16v8;
typedef __attribute__((ext_vector_type(4))) float f32x4;

#define GLL16(g, lptr) __builtin_amdgcn_global_load_lds( \
    (const __attribute__((address_space(1))) void*)(g),  \
    (__attribute__((address_space(3))) void*)(lptr), 16, 0, 0)

static __device__ __forceinline__ unsigned short f2bf(float f) {
  union { float f; uint32_t u; } v; v.f = f;
  uint32_t u = v.u;
  return (unsigned short)((u + 0x7FFFu + ((u >> 16) & 1u)) >> 16);  // RNE
}

static __device__ __forceinline__ float bf2f(unsigned short u) {
  union { uint32_t u; float f; } v; v.u = ((uint32_t)u) << 16;
  return v.f;
}

// fp32x8 -> bf16x8 via compiler-selected v_cvt_pk_bf16_f32 (RNE)
static __device__ __forceinline__ bf16x8 cvt8(float4 a, float4 b) {
  f32x8 v = {a.x, a.y, a.z, a.w, b.x, b.y, b.z, b.w};
  bf16v8 c = __builtin_convertvector(v, bf16v8);
  bf16x8 r;
  __builtin_memcpy(&r, &c, 16);
  return r;
}

// tanh(x) = 1 - 2/(1+e^{2x}); exact at +-inf, ~1e-6 abs err (v_exp+v_rcp).
static __device__ __forceinline__ float tanh_fast(float x) {
  const float e = __expf(2.0f * x);
  const float r = __builtin_amdgcn_rcpf(1.0f + e);
  return __builtin_fmaf(-2.0f, r, 1.0f);
}

// ---------------- K0a: W_enc [2048][512] f32 -> Bt [512][2048] bf16 ----------
__global__ void k_transpose_wenc(const float* __restrict__ W,
                                 unsigned short* __restrict__ Bt) {
  __shared__ float tile[32][33];
  const int kt = blockIdx.x;
  const int nt = blockIdx.y;
  const int tx = threadIdx.x, ty = threadIdx.y;   // 32 x 8
#pragma unroll
  for (int j = 0; j < 4; j++)
    tile[ty + 8*j][tx] = W[(size_t)(kt*32 + ty + 8*j)*ADIM + nt*32 + tx];
  __syncthreads();
#pragma unroll
  for (int j = 0; j < 4; j++)
    Bt[(size_t)(nt*32 + ty + 8*j)*EDIM + kt*32 + tx] = f2bf(tile[tx][ty + 8*j]);
}

// ------ K0b: att2p = hidden @ W_dec + b_dec + b_enc (b_enc folded in) -------
__global__ void k_att2p(const float* __restrict__ H, const float* __restrict__ Wd,
                        const float* __restrict__ bd, const float* __restrict__ be,
                        float* __restrict__ att2p) {
  __shared__ float h[DDIM];
  const int b = blockIdx.x;
  const int t = threadIdx.x;            // 256
  h[t]       = H[(size_t)b*DDIM + t];
  h[t + 256] = H[(size_t)b*DDIM + t + 256];
  __syncthreads();
  float a0 = 0.f, a1 = 0.f;
#pragma unroll 8
  for (int k = 0; k < DDIM; k++) {
    const float hv = h[k];
    a0 += hv * Wd[(size_t)k*ADIM + t];
    a1 += hv * Wd[(size_t)k*ADIM + t + 256];
  }
  att2p[(size_t)b*ADIM + t]       = a0 + bd[t]       + be[t];
  att2p[(size_t)b*ADIM + t + 256] = a1 + bd[t + 256] + be[t + 256];
}

// ---------------- K0c: enc fp32 -> encbf bf16 (grid-stride, BW-bound) -------
__global__ __launch_bounds__(256) void k_preconvert(const float* __restrict__ in,
                                                    unsigned short* __restrict__ out,
                                                    long n8) {
  long i = (long)blockIdx.x * 256 + threadIdx.x;
  const long stride = (long)gridDim.x * 256;
  for (; i < n8; i += stride) {
    const float4* p = (const float4*)(in + i*8);
    const float4 a = p[0], b = p[1];
    *(bf16x8*)(out + i*8) = cvt8(a, b);
  }
}

// ---------------- K1-bf16: m97 GEMM, 3-buf counted vmcnt, fast epilogue -----
// Scores written as 8 private partial slices (N-block x wc), plain stores:
// no memset, no atomics. smctx sums the slices.
__global__ __launch_bounds__(256, 3) void k_gemm_bf16(
    const unsigned short* __restrict__ At,  // [M][2048] bf16 (encbf)
    const unsigned short* __restrict__ Bt,  // [512][2048] bf16
    const float* __restrict__ att2p,        // [B][512] (b_enc folded)
    const float* __restrict__ W_full,       // [512]
    float* __restrict__ spart)              // [8][M] partial scores
{
  __shared__ __align__(16) char ldsA[3*8192];   // [buf][128 rows][32 bf16]
  __shared__ __align__(16) char ldsB[3*8192];
  __shared__ float a2s[2][128];                 // att2p slices for <=2 batches

  const int t   = threadIdx.x;          // 0..255
  const int l   = t & 63;
  const int wid = t >> 6;               // 0..3
  const int wr  = wid >> 1;             // 0..1 (M)
  const int wc  = wid & 1;              // 0..1 (N)

  // XCD swizzle (nwg=3136=8*392), n-minor: 4 N-tiles of one M-tile run
  // consecutively on one XCD -> A-tile fetched once, L2-reused 4x.
  const int orig = blockIdx.x;
  const int tile = (orig & 7) * 392 + (orig >> 3);
  const int bm0 = (tile >> 2) * BM;
  const int bn0 = (tile & 3) * BN;

  // ---- att2p staging: rows bm0..bm0+127 span batches ab0..ab1 (<=2) ----
  const int ab0 = bm0 / 196;
  const int ab1 = (bm0 + BM - 1) / 196;
  {
    const int slot = t >> 7, c = t & 127;       // 256 threads = 2x128
    a2s[slot][c] = att2p[(size_t)(slot ? ab1 : ab0) * ADIM + bn0 + c];
  }

  // ---- staging maps: idx=j*256+t -> row=idx>>2, chunk c=idx&3;
  //      LDS (row,c) holds global chunk c^((row>>1)&3); dest linear idx*16 ----
  const int r0 = t >> 2, c0 = t & 3;
  const int cswz = (c0 ^ ((r0 >> 1) & 3)) * 8;
  const unsigned short* srcA0 = At + (size_t)(bm0 + r0      ) * EDIM + cswz;
  const unsigned short* srcA1 = At + (size_t)(bm0 + r0 + 64 ) * EDIM + cswz;
  const unsigned short* srcB0 = Bt + (size_t)(bn0 + r0      ) * EDIM + cswz;
  const unsigned short* srcB1 = Bt + (size_t)(bn0 + r0 + 64 ) * EDIM + cswz;
  const int d0 = wid * 1024;            // j=0 dest (+lane*16 implicit)
  const int d1 = 4096 + wid * 1024;     // j=1 dest

  // ---- fragment read addresses ----
  const int l15 = l & 15, hi = l >> 4;
  const int ck  = (hi ^ ((l15 >> 1) & 3)) * 16;
  const int baseA = wr*4096 + l15*64 + ck;   // + mi*1024 + buf*8192
  const int baseB = wc*4096 + l15*64 + ck;   // + ni*1024 + buf*8192

  f32x4 acc[4][4] = {};

#define STG(BUF, KT) do {                                        \
    GLL16(srcA0 + (size_t)(KT)*BK, ldsA + (BUF)*8192 + d0);      \
    GLL16(srcA1 + (size_t)(KT)*BK, ldsA + (BUF)*8192 + d1);      \
    GLL16(srcB0 + (size_t)(KT)*BK, ldsB + (BUF)*8192 + d0);      \
    GLL16(srcB1 + (size_t)(KT)*BK, ldsB + (BUF)*8192 + d1);      \
  } while (0)

#define CMP(BUF) do {                                            \
    bf16x8 af[4], bfr[4];                                        \
    _Pragma("unroll")                                            \
    for (int ni = 0; ni < 4; ni++)                               \
      bfr[ni] = *(const bf16x8*)(ldsB + (BUF)*8192 + ni*1024 + baseB); \
    _Pragma("unroll")                                            \
    for (int mi = 0; mi < 4; mi++)                               \
      af[mi] = *(const bf16x8*)(ldsA + (BUF)*8192 + mi*1024 + baseA); \
    _Pragma("unroll")                                            \
    for (int mi = 0; mi < 4; mi++)                               \
      _Pragma("unroll")                                          \
      for (int ni = 0; ni < 4; ni++)                             \
        acc[mi][ni] = __builtin_amdgcn_mfma_f32_16x16x32_bf16(   \
            af[mi], bfr[ni], acc[mi][ni], 0, 0, 0);              \
  } while (0)

#define TILE(T, BUF, BUF2) do {                                  \
    STG(BUF2, (T)+2);                                            \
    CMP(BUF);                                                    \
    asm volatile("s_waitcnt vmcnt(4)" ::: "memory");             \
    __builtin_amdgcn_s_barrier();                                \
  } while (0)

  // ---- prologue: stage tiles 0,1 ----
  STG(0, 0);
  STG(1, 1);
  asm volatile("s_waitcnt vmcnt(4)" ::: "memory");   // tile 0 done
  __builtin_amdgcn_s_barrier();

  // ---- tiles 0..61 (period 3) ----
  for (int kb = 0; kb < 60; kb += 3) {
    TILE(kb,     0, 2);
    TILE(kb + 1, 1, 0);
    TILE(kb + 2, 2, 1);
  }
  TILE(60, 0, 2);    // stages 62
  TILE(61, 1, 0);    // stages 63
  // ---- tile 62: nothing to stage; drain tile 63 ----
  CMP(2);
  asm volatile("s_waitcnt vmcnt(0)" ::: "memory");
  __builtin_amdgcn_s_barrier();
  // ---- tile 63 ----
  CMP(0);

  // ---- fast epilogue: partial = sum_cols tanh_fast(acc + att2p) * W_full ----
  float* myslice = spart + (size_t)((tile & 3) * 2 + wc) * MROWS;
  float wf[4];
  int cidx[4];
#pragma unroll
  for (int ni = 0; ni < 4; ni++) {
    cidx[ni] = wc*64 + ni*16 + l15;
    wf[ni] = W_full[bn0 + cidx[ni]];
  }
#pragma unroll
  for (int mi = 0; mi < 4; mi++) {
#pragma unroll
    for (int e = 0; e < 4; e++) {
      const int row_l = wr*64 + mi*16 + hi*4 + e;
      const unsigned gr = (unsigned)(bm0 + row_l);
      const int slot = (int)(gr / 196u) - ab0;   // 0 or 1
      float s = 0.f;
#pragma unroll
      for (int ni = 0; ni < 4; ni++) {
        const float v = acc[mi][ni][e] + a2s[slot][cidx[ni]];
        s += tanh_fast(v) * wf[ni];
      }
      s += __shfl_xor(s, 1); s += __shfl_xor(s, 2);
      s += __shfl_xor(s, 4); s += __shfl_xor(s, 8);
      if (l15 == 0) myslice[gr] = s;
    }
  }
}

// -------- K2-fused: sum partials + softmax (196) + context, 1 block/batch ---
__global__ __launch_bounds__(256) void k_smctx_bf16(
    const unsigned short* __restrict__ encbf,
    const float* __restrict__ spart,     // [8][M] partial scores
    float* __restrict__ alpha,           // [512][196] out
    float* __restrict__ ctx) {           // [512][2048] out
  __shared__ float red[256];
  __shared__ float al[PIX];
  const int b = blockIdx.x, t = threadIdx.x;

  float v = -1e30f;
  if (t < PIX) {
    const size_t idx = (size_t)b * PIX + t;
    v = 0.f;
#pragma unroll
    for (int k = 0; k < 8; k++)
      v += spart[(size_t)k * MROWS + idx];
  }
  red[t] = v; __syncthreads();
  for (int s2 = 128; s2 > 0; s2 >>= 1) {
    if (t < s2) red[t] = fmaxf(red[t], red[t + s2]);
    __syncthreads();
  }
  const float m = red[0]; __syncthreads();
  const float e = (t < PIX) ? __expf(v - m) : 0.f;
  red[t] = e; __syncthreads();
  for (int s2 = 128; s2 > 0; s2 >>= 1) {
    if (t < s2) red[t] += red[t + s2];
    __syncthreads();
  }
  const float inv = 1.f / red[0];
  if (t < PIX) {
    const float a = e * inv;
    al[t] = a;
    alpha[(size_t)b*PIX + t] = a;
  }
  __syncthreads();

  const unsigned short* ep = encbf + (size_t)b * PIX * EDIM + t * 8;
  float acc[8] = {};
  for (int p = 0; p < PIX; p++) {
    const bf16x8 vv = *(const bf16x8*)(ep + (size_t)p * EDIM);
    const float a = al[p];
#pragma unroll
    for (int j = 0; j < 8; j++)
      acc[j] += a * bf2f((unsigned short)vv[j]);
  }
  float4 o0 = {acc[0], acc[1], acc[2], acc[3]};
  float4 o1 = {acc[4], acc[5], acc[6], acc[7]};
  float4* dst = (float4*)(ctx + (size_t)b * EDIM + t * 8);
  dst[0] = o0; dst[1] = o1;
}

// ================= FALLBACK PATH (fp32-A, used if ws too small) =============
__global__ void k_softmax(float* __restrict__ sa) {   // [512][196]
  __shared__ float red[256];
  const int b = blockIdx.x, t = threadIdx.x;
  const float v = (t < PIX) ? sa[(size_t)b*PIX + t] : -1e30f;
  red[t] = v; __syncthreads();
  for (int s2 = 128; s2 > 0; s2 >>= 1) {
    if (t < s2) red[t] = fmaxf(red[t], red[t + s2]);
    __syncthreads();
  }
  const float m = red[0]; __syncthreads();
  const float e = (t < PIX) ? __expf(v - m) : 0.f;
  red[t] = e; __syncthreads();
  for (int s2 = 128; s2 > 0; s2 >>= 1) {
    if (t < s2) red[t] += red[t + s2];
    __syncthreads();
  }
  const float inv = 1.f / red[0];
  if (t < PIX) sa[(size_t)b*PIX + t] = e * inv;
}

__global__ __launch_bounds__(256, 3) void k_gemm_scores(
    const float* __restrict__ enc, const unsigned short* __restrict__ Bt,
    const float* __restrict__ att2p, const float* __restrict__ W_full,
    float* __restrict__ scores) {
  __shared__ __align__(16) char ldsA[2*8192];
  __shared__ __align__(16) char ldsB[3*8192];
  __shared__ float a2s[2][128];
  const int t = threadIdx.x, l = t & 63, wid = t >> 6;
  const int wr = wid >> 1, wc = wid & 1;
  const int orig = blockIdx.x;
  const int tile = (orig & 7) * 392 + (orig >> 3);
  const int bm0 = (tile >> 2) * BM, bn0 = (tile & 3) * BN;
  const int ab0 = bm0 / 196;
  const int ab1 = (bm0 + BM - 1) / 196;
  {
    const int slot = t >> 7, c = t & 127;
    a2s[slot][c] = att2p[(size_t)(slot ? ab1 : ab0) * ADIM + bn0 + c];
  }
  const int arow = t >> 1;
  const float* srcA = enc + (size_t)(bm0 + arow) * EDIM + (t & 1) * 16;
  const int g0 = (t & 1) * 2;
  const int wA0 = arow*64 + (((g0    ) ^ ((arow >> 1) & 3)) * 16);
  const int wA1 = arow*64 + (((g0 + 1) ^ ((arow >> 1) & 3)) * 16);
  const unsigned short* srcB[2];
#pragma unroll
  for (int j = 0; j < 2; j++) {
    const int idx = j*256 + t; const int row = idx >> 2;
    srcB[j] = Bt + (size_t)(bn0 + row) * EDIM + ((idx & 3) ^ ((row >> 1) & 3)) * 8;
  }
  const int dB = wid * 1024;
  const int l15 = l & 15, hi = l >> 4;
  const int ck = (hi ^ ((l15 >> 1) & 3)) * 16;
  const int baseA = wr*4096 + l15*64 + ck;
  const int baseB = wc*4096 + l15*64 + ck;
  float4 ar[2][4];
  f32x4 acc[4][4] = {};
#define F_A_ISSUE(SLOT, KT) do { const float* _s = srcA + (size_t)(KT) * BK; \
    ar[SLOT][0] = *(const float4*)(_s); ar[SLOT][1] = *(const float4*)(_s + 4); \
    ar[SLOT][2] = *(const float4*)(_s + 8); ar[SLOT][3] = *(const float4*)(_s + 12); } while (0)
#define F_B_GLL(BUF, KT) do { \
    GLL16(srcB[0] + (size_t)(KT)*BK, ldsB + (BUF)*8192 + dB); \
    GLL16(srcB[1] + (size_t)(KT)*BK, ldsB + (BUF)*8192 + 4096 + dB); } while (0)
#define F_A_WRITE(LBUF, SLOT) do { \
    bf16x8 w0 = cvt8(ar[SLOT][0], ar[SLOT][1]); bf16x8 w1 = cvt8(ar[SLOT][2], ar[SLOT][3]); \
    *(bf16x8*)(ldsA + (LBUF)*8192 + wA0) = w0; *(bf16x8*)(ldsA + (LBUF)*8192 + wA1) = w1; } while (0)
#define F_COMPUTE(BA, BB) do { bf16x8 af[4], bfr[4]; \
    _Pragma("unroll") for (int ni = 0; ni < 4; ni++) \
      bfr[ni] = *(const bf16x8*)(ldsB + (BB)*8192 + ni*1024 + baseB); \
    _Pragma("unroll") for (int mi = 0; mi < 4; mi++) \
      af[mi] = *(const bf16x8*)(ldsA + (BA)*8192 + mi*1024 + baseA); \
    _Pragma("unroll") for (int mi = 0; mi < 4; mi++) \
      _Pragma("unroll") for (int ni = 0; ni < 4; ni++) \
        acc[mi][ni] = __builtin_amdgcn_mfma_f32_16x16x32_bf16(af[mi], bfr[ni], acc[mi][ni], 0, 0, 0); } while (0)
#define F_TILE(T, CUR, BB, BBS) do { F_A_ISSUE(CUR, (T)+2); F_B_GLL(BBS, (T)+2); \
    F_COMPUTE(CUR, BB); asm volatile("s_waitcnt vmcnt(6)" ::: "memory"); \
    F_A_WRITE((CUR)^1, (CUR)^1); asm volatile("s_waitcnt lgkmcnt(0)" ::: "memory"); \
    __builtin_amdgcn_s_barrier(); } while (0)
  F_A_ISSUE(0, 0); F_B_GLL(0, 0); F_A_ISSUE(1, 1); F_B_GLL(1, 1);
  asm volatile("s_waitcnt vmcnt(8)" ::: "memory");
  F_A_WRITE(0, 0);
  asm volatile("s_waitcnt vmcnt(6) lgkmcnt(0)" ::: "memory");
  __builtin_amdgcn_s_barrier();
  for (int kb = 0; kb < 60; kb += 6) {
    F_TILE(kb+0, 0, 0, 2); F_TILE(kb+1, 1, 1, 0); F_TILE(kb+2, 0, 2, 1);
    F_TILE(kb+3, 1, 0, 2); F_TILE(kb+4, 0, 1, 0); F_TILE(kb+5, 1, 2, 1);
  }
  F_TILE(60, 0, 0, 2); F_TILE(61, 1, 1, 0);
  { F_COMPUTE(0, 2); asm volatile("s_waitcnt vmcnt(2)" ::: "memory");
    F_A_WRITE(1, 1); asm volatile("s_waitcnt vmcnt(0) lgkmcnt(0)" ::: "memory");
    __builtin_amdgcn_s_barrier(); }
  F_COMPUTE(1, 0);
  float wf[4]; int cidx[4];
#pragma unroll
  for (int ni = 0; ni < 4; ni++) {
    cidx[ni] = wc*64 + ni*16 + l15;
    wf[ni] = W_full[bn0 + cidx[ni]];
  }
#pragma unroll
  for (int mi = 0; mi < 4; mi++) {
#pragma unroll
    for (int e = 0; e < 4; e++) {
      const int row_l = wr*64 + mi*16 + hi*4 + e;
      const unsigned gr = (unsigned)(bm0 + row_l);
      const int slot = (int)(gr / 196u) - ab0;
      float s = 0.f;
#pragma unroll
      for (int ni = 0; ni < 4; ni++) {
        const float v = acc[mi][ni][e] + a2s[slot][cidx[ni]];
        s += tanh_fast(v) * wf[ni];
      }
      s += __shfl_xor(s, 1); s += __shfl_xor(s, 2);
      s += __shfl_xor(s, 4); s += __shfl_xor(s, 8);
      if (l15 == 0) atomicAdd(&scores[gr], s);
    }
  }
}

__global__ __launch_bounds__(512) void k_context(
    const float* __restrict__ enc, const float* __restrict__ alpha,
    float* __restrict__ ctx) {
  __shared__ float al[PIX];
  const int b = blockIdx.x, t = threadIdx.x;
  if (t < PIX) al[t] = alpha[(size_t)b*PIX + t];
  __syncthreads();
  const float4* e4 = (const float4*)(enc + (size_t)b * PIX * EDIM);
  float4 acc = {0.f, 0.f, 0.f, 0.f};
#pragma unroll 4
  for (int p = 0; p < PIX; p++) {
    const float4 v = e4[(size_t)p * (EDIM/4) + t];
    const float a = al[p];
    acc.x += v.x * a; acc.y += v.y * a; acc.z += v.z * a; acc.w += v.w * a;
  }
  ((float4*)(ctx + (size_t)b * EDIM))[t] = acc;
}

// ---------------------------------------------------------------------------
extern "C" void kernel_launch(void* const* d_in, const int* in_sizes, int n_in,
                              void* d_out, int out_size, void* d_ws, size_t ws_size,
                              hipStream_t stream) {
  (void)in_sizes; (void)n_in; (void)out_size;
  const float* enc   = (const float*)d_in[0];
  const float* hid   = (const float*)d_in[1];
  const float* Wenc  = (const float*)d_in[2];
  const float* benc  = (const float*)d_in[3];
  const float* Wdec  = (const float*)d_in[4];
  const float* bdec  = (const float*)d_in[5];
  const float* Wfull = (const float*)d_in[6];
  // d_in[7] = b_full: softmax-invariant, unused.

  float* ctx   = (float*)d_out;
  float* alpha = (float*)d_out + (size_t)BATCH * EDIM;

  const size_t encbf_b = (size_t)MROWS * EDIM * 2;       // 411,041,792
  const size_t bt_b    = (size_t)ADIM * EDIM * 2;        //   2,097,152
  const size_t att2_b  = (size_t)BATCH * ADIM * 4;       //   1,048,576
  const size_t spart_b = (size_t)8 * MROWS * 4;          //   3,211,264

  if (ws_size >= encbf_b + bt_b + att2_b + spart_b) {
    // ---- bf16-preconvert path (no memset, no atomics) ----
    unsigned short* encbf = (unsigned short*)d_ws;
    unsigned short* Bt    = (unsigned short*)((char*)d_ws + encbf_b);
    float*          att2p = (float*)((char*)d_ws + encbf_b + bt_b);
    float*          spart = (float*)((char*)d_ws + encbf_b + bt_b + att2_b);

    k_transpose_wenc<<<dim3(64, 16), dim3(32, 8), 0, stream>>>(Wenc, Bt);
    k_att2p<<<BATCH, 256, 0, stream>>>(hid, Wdec, bdec, benc, att2p);
    k_preconvert<<<2048, 256, 0, stream>>>(enc, encbf, (long)MROWS * EDIM / 8);
    k_gemm_bf16<<<3136, 256, 0, stream>>>(encbf, Bt, att2p, Wfull, spart);
    k_smctx_bf16<<<BATCH, 256, 0, stream>>>(encbf, spart, alpha, ctx);
  } else {
    // ---- fallback: fp32-A path ----
    unsigned short* Bt    = (unsigned short*)d_ws;
    float*          att2p = (float*)((char*)d_ws + bt_b);

    hipMemsetAsync(alpha, 0, (size_t)MROWS * sizeof(float), stream);
    k_transpose_wenc<<<dim3(64, 16), dim3(32, 8), 0, stream>>>(Wenc, Bt);
    k_att2p<<<BATCH, 256, 0, stream>>>(hid, Wdec, bdec, benc, att2p);
    k_gemm_scores<<<3136, 256, 0, stream>>>(enc, Bt, att2p, Wfull, alpha);
    k_softmax<<<BATCH, 256, 0, stream>>>(alpha);
    k_context<<<BATCH, 512, 0, stream>>>(enc, alpha, ctx);
  }
}